// Round 14
// baseline (1469.975 us; speedup 1.0000x reference)
//
#include <hip/hip_runtime.h>
#include <hip/hip_bf16.h>
#include <math.h>

#define N1     30000          // nodes per branch
#define NT     60000          // merged nodes
#define E1     480000
#define NG     64             // graphs per branch
#define NGT    128            // merged graphs
#define DIN    20
#define DD     512
#define NH     4
#define CH     128
#define NHID   128
#define PSPLIT 8
#define BN_EPS 1e-5f

typedef __attribute__((ext_vector_type(8))) short bf16x8;
typedef __attribute__((ext_vector_type(4))) float f32x4;
typedef __attribute__((address_space(1))) const void cg_void;
typedef __attribute__((address_space(3))) void lds_void;

__device__ inline unsigned short f2b(float f) {
    __hip_bfloat16 h = __float2bfloat16(f);
    return *(unsigned short*)&h;
}
__device__ inline float b2f(unsigned short u) {
    return __uint_as_float(((unsigned)u) << 16);
}

// ------------------------------------------------------------ merge helpers
__global__ __launch_bounds__(256) void k_xmerge(const float* __restrict__ a,
                                                const float* __restrict__ b,
                                                float* __restrict__ xm) {
    int i = blockIdx.x * 256 + threadIdx.x;
    int tot = NT * DIN;
    if (i < tot) xm[i] = (i < N1 * DIN) ? a[i] : b[i - N1 * DIN];
}

__global__ __launch_bounds__(256) void k_bmerge(const int* __restrict__ a,
                                                const int* __restrict__ b,
                                                int* __restrict__ bm) {
    int i = blockIdx.x * 256 + threadIdx.x;
    if (i < NT) bm[i] = (i < N1) ? a[i] : b[i - N1] + NG;
}

// ---------------------------------------------------------------- CSR build
__global__ __launch_bounds__(256) void k_hist2(const int* __restrict__ dwl,
                                               const int* __restrict__ dmt,
                                               int* __restrict__ cnt) {
    for (int e = blockIdx.x * blockDim.x + threadIdx.x; e < E1;
         e += gridDim.x * blockDim.x) {
        atomicAdd(&cnt[dwl[e]], 1);
        atomicAdd(&cnt[dmt[e] + N1], 1);
    }
}

__global__ __launch_bounds__(512) void k_scan2(const int* __restrict__ cnt,
                                               int* __restrict__ rowptr,
                                               int* __restrict__ cursor, int n) {
    __shared__ int sd[512];
    int t = threadIdx.x;
    int per = (n + 511) / 512;
    int lo = t * per, hi = lo + per;
    if (hi > n) hi = n;
    int s = 0;
    for (int i = lo; i < hi; ++i) s += cnt[i];
    sd[t] = s;
    __syncthreads();
    for (int off = 1; off < 512; off <<= 1) {
        int v = (t >= off) ? sd[t - off] : 0;
        __syncthreads();
        sd[t] += v;
        __syncthreads();
    }
    int run = sd[t] - s;
    for (int i = lo; i < hi; ++i) {
        rowptr[i] = run;
        cursor[i] = run;
        run += cnt[i];
    }
    if (t == 511) rowptr[n] = sd[511];
}

__global__ __launch_bounds__(256) void k_scatter2(const int* __restrict__ swl,
                                                  const int* __restrict__ dwl,
                                                  const int* __restrict__ smt,
                                                  const int* __restrict__ dmt,
                                                  int* __restrict__ cursor,
                                                  int* __restrict__ col) {
    for (int e = blockIdx.x * blockDim.x + threadIdx.x; e < E1;
         e += gridDim.x * blockDim.x) {
        int d0 = dwl[e];
        col[atomicAdd(&cursor[d0], 1)] = swl[e];
        int d1 = dmt[e] + N1;
        col[atomicAdd(&cursor[d1], 1)] = smt[e] + N1;
    }
}

// ---------------------------------------------------------- weight conv+transp
__global__ __launch_bounds__(256) void k_wconv(const float* __restrict__ W,
                                               unsigned short* __restrict__ Wt) {
    int n = blockIdx.x;
    for (int k = threadIdx.x; k < DD; k += 256)
        Wt[n * DD + k] = f2b(W[k * DD + n]);
}

// ------------------------------------------------------------- GIN1 agg (20)
__global__ __launch_bounds__(256) void k_gin1_agg(const float* __restrict__ x,
                                                  const int* __restrict__ rowptr,
                                                  const int* __restrict__ col,
                                                  float* __restrict__ out) {
    int node = blockIdx.x * 4 + (threadIdx.x >> 6);
    int lane = threadIdx.x & 63;
    if (node >= NT) return;
    int p0 = rowptr[node], p1 = rowptr[node + 1];
    float acc = 0.f;
    if (lane < DIN) acc = x[(size_t)node * DIN + lane];
    for (int j = p0; j < p1; ++j) {
        int s = col[j];
        if (lane < DIN) acc += x[(size_t)s * DIN + lane];
    }
    if (lane < DIN) out[(size_t)node * DIN + lane] = acc;
}

// ------------------------------------- GEMM [NT,20]@[20,512]+relu -> bf16 out
__global__ __launch_bounds__(256) void k_gemm20(const float* __restrict__ A,
                                                const float* __restrict__ W,
                                                const float* __restrict__ bias,
                                                unsigned short* __restrict__ C) {
    __shared__ float Ws[DIN][128];
    __shared__ float As[64][DIN + 1];
    int t = threadIdx.x;
    int row0 = blockIdx.x * 64;
    int col0 = blockIdx.y * 128;
    for (int i = t; i < DIN * 128; i += 256) {
        int k = i >> 7, c = i & 127;
        Ws[k][c] = W[k * DD + col0 + c];
    }
    for (int i = t; i < 64 * DIN; i += 256) {
        int r = i / DIN, k = i % DIN;
        int rr = row0 + r;
        if (rr >= NT) rr = NT - 1;
        As[r][k] = A[(size_t)rr * DIN + k];
    }
    __syncthreads();
    int c4 = (t & 31) * 4;
    int r0 = (t >> 5) * 8;
    float acc[8][4];
#pragma unroll
    for (int i = 0; i < 8; i++)
#pragma unroll
        for (int j = 0; j < 4; j++) acc[i][j] = 0.f;
    for (int k = 0; k < DIN; k++) {
        float4 b = *(const float4*)&Ws[k][c4];
#pragma unroll
        for (int i = 0; i < 8; i++) {
            float a = As[r0 + i][k];
            acc[i][0] += a * b.x; acc[i][1] += a * b.y;
            acc[i][2] += a * b.z; acc[i][3] += a * b.w;
        }
    }
    float4 bb = *(const float4*)&bias[col0 + c4];
#pragma unroll
    for (int i = 0; i < 8; i++) {
        int r = row0 + r0 + i;
        if (r < NT) {
            short4 o;
            o.x = (short)f2b(fmaxf(acc[i][0] + bb.x, 0.f));
            o.y = (short)f2b(fmaxf(acc[i][1] + bb.y, 0.f));
            o.z = (short)f2b(fmaxf(acc[i][2] + bb.z, 0.f));
            o.w = (short)f2b(fmaxf(acc[i][3] + bb.w, 0.f));
            *(short4*)&C[(size_t)r * DD + col0 + c4] = o;
        }
    }
}

// ------------------------------- MFMA GEMM [M,512](bf16) @ Wt[512,512](bf16^T)
// 256x128 tile, BK=64, gload_lds staging, source-side XOR swizzle.
// 4 waves; wave w owns rows [w*64, w*64+64) x all 128 cols: acc[4][8].
// MODE: 0 = bf16 out + bias; 1 = + relu; 2 = no bias + a_s/a_d epilogue (GAT)
template <int MODE>
__global__ __launch_bounds__(256) void k_gemm_mfma(
    const unsigned short* __restrict__ A, const unsigned short* __restrict__ Wt,
    const float* __restrict__ bias, unsigned short* __restrict__ Cb,
    const float* __restrict__ att_s, const float* __restrict__ att_d,
    float* __restrict__ as_o, float* __restrict__ ad_o, int M) {
    __shared__ unsigned short AsU[256 * 64];   // 32 KB; reused as st[128][128]
    __shared__ unsigned short BsU[128 * 64];   // 16 KB
    __shared__ float s_att[2 * 256];           // MODE 2 only

    int t = threadIdx.x;
    int lane = t & 63;
    int w = t >> 6;
    int bid = blockIdx.x;
    int row0 = (bid >> 2) * 256;
    int ct = bid & 3;
    int col0 = ct * 128;

    int l8 = lane >> 3;                 // row within 8-row staging group
    int swz = (lane & 7) ^ l8;          // source k-slot permutation

    f32x4 acc[4][8];
#pragma unroll
    for (int i = 0; i < 4; i++)
#pragma unroll
        for (int j = 0; j < 8; j++) acc[i][j] = (f32x4){0.f, 0.f, 0.f, 0.f};

    int fr = lane & 15, fq = lane >> 4, f7 = lane & 7;

    for (int s = 0; s < 8; ++s) {
        int k0 = s * 64;
        __syncthreads();                 // prev-step fragment reads done
        // A: wave w stages rows [w*64, w*64+64): 8 gloads of 8 rows
#pragma unroll
        for (int q = 0; q < 8; q++) {
            int rowbase = w * 64 + q * 8;
            int gr = row0 + rowbase + l8;
            if (gr >= M) gr = M - 1;
            const unsigned short* srcA = A + (size_t)gr * DD + k0 + swz * 8;
            __builtin_amdgcn_global_load_lds((cg_void*)srcA,
                                             (lds_void*)(AsU + rowbase * 64),
                                             16, 0, 0);
        }
        // B: wave w stages rows [w*32, w*32+32): 4 gloads
#pragma unroll
        for (int q = 0; q < 4; q++) {
            int rowbase = w * 32 + q * 8;
            const unsigned short* srcB = Wt +
                (size_t)(col0 + rowbase + l8) * DD + k0 + swz * 8;
            __builtin_amdgcn_global_load_lds((cg_void*)srcB,
                                             (lds_void*)(BsU + rowbase * 64),
                                             16, 0, 0);
        }
        __syncthreads();                 // vmcnt(0) drained by compiler
#pragma unroll
        for (int kk = 0; kk < 2; kk++) {
            bf16x8 am[4], bn[8];
#pragma unroll
            for (int i = 0; i < 4; i++) {
                int row = w * 64 + i * 16 + fr;       // row&7 == lane&7
                int ks = (kk * 4 + fq) ^ f7;
                am[i] = *(const bf16x8*)&AsU[row * 64 + ks * 8];
            }
#pragma unroll
            for (int j = 0; j < 8; j++) {
                int row = j * 16 + fr;
                int ks = (kk * 4 + fq) ^ f7;
                bn[j] = *(const bf16x8*)&BsU[row * 64 + ks * 8];
            }
#pragma unroll
            for (int i = 0; i < 4; i++)
#pragma unroll
                for (int j = 0; j < 8; j++)
                    acc[i][j] = __builtin_amdgcn_mfma_f32_16x16x32_bf16(
                        am[i], bn[j], acc[i][j], 0, 0, 0);
        }
    }

    // ---------------- epilogue: 2-half LDS-staged coalesced store ----------
    __syncthreads();                     // all fragment reads done; reuse AsU
    unsigned short* st = AsU;            // [128][128] ushort = 32KB
    float bv[8], fa[8], fd[8];
#pragma unroll
    for (int j = 0; j < 8; j++) {
        int c = j * 16 + fr;
        if (MODE == 2) {
            fa[j] = att_s[ct * CH + c];
            fd[j] = att_d[ct * CH + c];
        } else {
            bv[j] = bias[col0 + c];
        }
    }
    if (MODE == 2) { s_att[t] = 0.f; s_att[256 + t] = 0.f; }
    __syncthreads();
    if (MODE == 2) {
#pragma unroll
        for (int i = 0; i < 4; i++) {
#pragma unroll
            for (int r = 0; r < 4; r++) {
                int lrow = w * 64 + i * 16 + fq * 4 + r;
                float ss = 0.f, sd = 0.f;
#pragma unroll
                for (int j = 0; j < 8; j++) {
                    ss += acc[i][j][r] * fa[j];
                    sd += acc[i][j][r] * fd[j];
                }
                atomicAdd(&s_att[lrow], ss);
                atomicAdd(&s_att[256 + lrow], sd);
            }
        }
    }
#pragma unroll
    for (int h = 0; h < 2; h++) {
        if ((w >> 1) == h) {             // waves 2h,2h+1 own this 128-row half
            int lr0 = (w & 1) * 64;
#pragma unroll
            for (int i = 0; i < 4; i++) {
#pragma unroll
                for (int r = 0; r < 4; r++) {
                    int lrow = lr0 + i * 16 + fq * 4 + r;
#pragma unroll
                    for (int j = 0; j < 8; j++) {
                        float v = acc[i][j][r];
                        if (MODE != 2) {
                            v += bv[j];
                            if (MODE == 1) v = fmaxf(v, 0.f);
                        }
                        st[lrow * 128 + j * 16 + fr] = f2b(v);
                    }
                }
            }
        }
        __syncthreads();                 // st writes (+ h=0: s_att atomics) done
        // coalesced readout: each 16-lane group covers one full 256B row
#pragma unroll
        for (int i = 0; i < 8; i++) {
            int idx = i * 256 + t;
            int row = idx >> 4, seg = idx & 15;
            int grow = row0 + h * 128 + row;
            if (grow < M) {
                int4 v = *(const int4*)&st[row * 128 + seg * 8];
                *(int4*)&Cb[(size_t)grow * DD + col0 + seg * 8] = v;
            }
        }
        __syncthreads();                 // readout done before st reuse
    }
    if (MODE == 2) {
        // t in 0..255 covers all 256 tile rows exactly once
        int grow = row0 + t;
        if (grow < M) {
            as_o[grow * NH + ct] = s_att[t];
            ad_o[grow * NH + ct] = s_att[256 + t];
        }
    }
}

// --------------------------- BatchNorm over bf16, two branch segments
__global__ __launch_bounds__(256) void k_bn_stats2b(const unsigned short* __restrict__ h,
                                                    float* __restrict__ sums) {
    int t = threadIdx.x;                 // channels 2t, 2t+1
    float sa[2] = {0.f, 0.f}, qa[2] = {0.f, 0.f};
    float sb[2] = {0.f, 0.f}, qb[2] = {0.f, 0.f};
    for (int r = blockIdx.x; r < NT; r += gridDim.x) {
        unsigned u = ((const unsigned*)(h + (size_t)r * DD))[t];
        float va = b2f((unsigned short)(u & 0xffff));
        float vb = b2f((unsigned short)(u >> 16));
        int seg = (r >= N1);
        sa[seg] += va; qa[seg] += va * va;
        sb[seg] += vb; qb[seg] += vb * vb;
    }
    int c = 2 * t;
#pragma unroll
    for (int seg = 0; seg < 2; ++seg) {
        atomicAdd(&sums[seg * DD + c], sa[seg]);
        atomicAdd(&sums[seg * DD + c + 1], sb[seg]);
        atomicAdd(&sums[2 * DD + seg * DD + c], qa[seg]);
        atomicAdd(&sums[2 * DD + seg * DD + c + 1], qb[seg]);
    }
}

__global__ __launch_bounds__(512) void k_bn_fin2(const float* __restrict__ sums,
                                                 const float* __restrict__ g,
                                                 const float* __restrict__ b,
                                                 float* __restrict__ sc) {
    int c = threadIdx.x;
#pragma unroll
    for (int seg = 0; seg < 2; ++seg) {
        float mean = sums[seg * DD + c] / (float)N1;
        float var = sums[2 * DD + seg * DD + c] / (float)N1 - mean * mean;
        float rs = rsqrtf(var + BN_EPS);
        float s = g[c] * rs;
        sc[seg * DD + c] = s;
        sc[2 * DD + seg * DD + c] = b[c] - mean * s;
    }
}

// BN apply + relu, in-place on bf16 buffer
__global__ __launch_bounds__(256) void k_bn_apply_ip(unsigned short* __restrict__ h,
                                                     const float* __restrict__ sc) {
    int total = NT * (DD / 8);
    for (int i = blockIdx.x * blockDim.x + threadIdx.x; i < total;
         i += gridDim.x * blockDim.x) {
        int4 v = ((int4*)h)[i];
        unsigned short* u = (unsigned short*)&v;
        int row = i >> 6;
        int seg = (row >= N1);
        int c = (i & 63) * 8;
        const float* scale = sc + seg * DD;
        const float* shift = sc + 2 * DD + seg * DD;
#pragma unroll
        for (int k = 0; k < 8; k++) {
            float f = b2f(u[k]) * scale[c + k] + shift[c + k];
            u[k] = f2b(fmaxf(f, 0.f));
        }
        ((int4*)h)[i] = v;
    }
}

// ---------- D=512 neighborhood sum fused with BN apply+relu (bf16 io) ----------
__global__ __launch_bounds__(256) void k_agg512f(const unsigned short* __restrict__ h,
                                                 const int* __restrict__ rowptr,
                                                 const int* __restrict__ col,
                                                 const float* __restrict__ sc,
                                                 unsigned short* __restrict__ out) {
    int node = blockIdx.x * 4 + (threadIdx.x >> 6);
    int lane = threadIdx.x & 63;
    if (node >= NT) return;
    int seg = (node >= N1);          // neighbors share the node's branch segment
    int cb = lane * 8;
    float scl[8], shf[8];
    *(float4*)&scl[0] = *(const float4*)&sc[seg * DD + cb];
    *(float4*)&scl[4] = *(const float4*)&sc[seg * DD + cb + 4];
    *(float4*)&shf[0] = *(const float4*)&sc[2 * DD + seg * DD + cb];
    *(float4*)&shf[4] = *(const float4*)&sc[2 * DD + seg * DD + cb + 4];

    size_t base = (size_t)node * DD + cb;
    float acc[8];
    {
        int4 v = *(const int4*)&h[base];
        const unsigned short* u = (const unsigned short*)&v;
#pragma unroll
        for (int i = 0; i < 8; i++)
            acc[i] = fmaxf(b2f(u[i]) * scl[i] + shf[i], 0.f);
    }
    int p0 = rowptr[node], p1 = rowptr[node + 1];
    int j = p0;
    for (; j + 1 < p1; j += 2) {
        int s0 = col[j], s1 = col[j + 1];
        int4 v0 = *(const int4*)&h[(size_t)s0 * DD + cb];
        int4 v1 = *(const int4*)&h[(size_t)s1 * DD + cb];
        const unsigned short* u0 = (const unsigned short*)&v0;
        const unsigned short* u1 = (const unsigned short*)&v1;
#pragma unroll
        for (int i = 0; i < 8; i++)
            acc[i] += fmaxf(b2f(u0[i]) * scl[i] + shf[i], 0.f) +
                      fmaxf(b2f(u1[i]) * scl[i] + shf[i], 0.f);
    }
    if (j < p1) {
        int4 v0 = *(const int4*)&h[(size_t)col[j] * DD + cb];
        const unsigned short* u0 = (const unsigned short*)&v0;
#pragma unroll
        for (int i = 0; i < 8; i++)
            acc[i] += fmaxf(b2f(u0[i]) * scl[i] + shf[i], 0.f);
    }
    int4 o;
    unsigned short* uo = (unsigned short*)&o;
#pragma unroll
    for (int i = 0; i < 8; i++) uo[i] = f2b(acc[i]);
    *(int4*)&out[base] = o;
}

// ------- GAT gather: inline softmax weights, bf16 per-node output
__global__ __launch_bounds__(256) void k_gat_gather(
    const unsigned short* __restrict__ hh, const float* __restrict__ a_s,
    const float* __restrict__ a_d, const int* __restrict__ rowptr,
    const int* __restrict__ col, unsigned short* __restrict__ outB) {
    int node = blockIdx.x * 4 + (threadIdx.x >> 6);
    int lane = threadIdx.x & 63;
    if (node >= NT) return;
    int h = lane >> 4;
    int idx4 = node * NH + h;
    float adi = a_d[idx4];
    float e = a_s[idx4] + adi;
    e = (e > 0.f) ? e : 0.2f * e;
    float ws = __expf(e);
    float den = ws;
    float acc[8];
    {
        int4 v = *(const int4*)&hh[(size_t)node * DD + lane * 8];
        const unsigned short* u = (const unsigned short*)&v;
#pragma unroll
        for (int i = 0; i < 8; i++) acc[i] = ws * b2f(u[i]);
    }
    int p0 = rowptr[node], p1 = rowptr[node + 1];
    int j = p0;
    for (; j + 1 < p1; j += 2) {
        int s0 = col[j], s1 = col[j + 1];
        float e0 = a_s[s0 * NH + h] + adi;
        float e1 = a_s[s1 * NH + h] + adi;
        e0 = (e0 > 0.f) ? e0 : 0.2f * e0;
        e1 = (e1 > 0.f) ? e1 : 0.2f * e1;
        float w0 = __expf(e0), w1 = __expf(e1);
        int4 v0 = *(const int4*)&hh[(size_t)s0 * DD + lane * 8];
        int4 v1 = *(const int4*)&hh[(size_t)s1 * DD + lane * 8];
        const unsigned short* u0 = (const unsigned short*)&v0;
        const unsigned short* u1 = (const unsigned short*)&v1;
#pragma unroll
        for (int i = 0; i < 8; i++) acc[i] += w0 * b2f(u0[i]) + w1 * b2f(u1[i]);
        den += w0 + w1;
    }
    if (j < p1) {
        int s0 = col[j];
        float e0 = a_s[s0 * NH + h] + adi;
        e0 = (e0 > 0.f) ? e0 : 0.2f * e0;
        float w0 = __expf(e0);
        int4 v0 = *(const int4*)&hh[(size_t)s0 * DD + lane * 8];
        const unsigned short* u0 = (const unsigned short*)&v0;
#pragma unroll
        for (int i = 0; i < 8; i++) acc[i] += w0 * b2f(u0[i]);
        den += w0;
    }
    float inv = 1.f / den;
    int4 o;
    unsigned short* uo = (unsigned short*)&o;
#pragma unroll
    for (int i = 0; i < 8; i++) uo[i] = f2b(acc[i] * inv);
    *(int4*)&outB[(size_t)node * DD + lane * 8] = o;
}

// ------------------------- two-stage segmented add-pool (sorted merged batch)
__device__ inline void graph_range(const int* __restrict__ bm, int g,
                                   int& start, int& end) {
    int lo = 0, hi = NT;
    while (lo < hi) { int m = (lo + hi) >> 1; if (bm[m] < g) lo = m + 1; else hi = m; }
    start = lo;
    hi = NT;
    while (lo < hi) { int m = (lo + hi) >> 1; if (bm[m] < g + 1) lo = m + 1; else hi = m; }
    end = lo;
}

__global__ __launch_bounds__(256) void k_pool1(const unsigned short* __restrict__ gatout,
                                               const int* __restrict__ bm,
                                               float* __restrict__ partial) {
    int g = blockIdx.x;
    int s = blockIdx.y;
    int t = threadIdx.x;                 // channels 2t, 2t+1
    int start, end;
    graph_range(bm, g, start, end);
    float a0 = 0.f, a1 = 0.f;
    for (int n = start + s; n < end; n += PSPLIT) {
        unsigned u = ((const unsigned*)(gatout + (size_t)n * DD))[t];
        a0 += b2f((unsigned short)(u & 0xffff));
        a1 += b2f((unsigned short)(u >> 16));
    }
    float* p = partial + ((size_t)g * PSPLIT + s) * DD;
    p[2 * t] = a0;
    p[2 * t + 1] = a1;
}

__global__ __launch_bounds__(512) void k_pool2(const float* __restrict__ partial,
                                               const int* __restrict__ bm,
                                               const float* __restrict__ bias,
                                               float* __restrict__ pool) {
    int g = blockIdx.x;
    int c = threadIdx.x;
    int start, end;
    graph_range(bm, g, start, end);
    float acc = 0.f;
#pragma unroll
    for (int s = 0; s < PSPLIT; ++s)
        acc += partial[((size_t)g * PSPLIT + s) * DD + c];
    pool[g * DD + c] = acc + (float)(end - start) * bias[c];
}

// ------------------------------------------------------------------- fc head
__global__ __launch_bounds__(256) void k_fc1(const float* __restrict__ gin,
                                             const float* __restrict__ W,
                                             const float* __restrict__ bias,
                                             float* __restrict__ out) {
    __shared__ float row[DD];
    int g = blockIdx.x;
    int t = threadIdx.x;
    row[t] = gin[g * DD + t];
    row[t + 256] = gin[g * DD + t + 256];
    __syncthreads();
    for (int cc = 0; cc < 2; ++cc) {
        int c = t + cc * 256;
        float acc = 0.f;
        for (int k = 0; k < DD; k++) acc += row[k] * W[k * DD + c];
        out[g * DD + c] = acc + bias[c];
    }
}

__global__ __launch_bounds__(512) void k_bn64_2(float* __restrict__ h,
                                                const float* __restrict__ g_,
                                                const float* __restrict__ b_) {
    int c = threadIdx.x;
#pragma unroll
    for (int seg = 0; seg < 2; ++seg) {
        float s = 0.f, q = 0.f;
        for (int r = 0; r < NG; r++) {
            float v = h[(seg * NG + r) * DD + c];
            s += v; q += v * v;
        }
        float mean = s / (float)NG;
        float var = q / (float)NG - mean * mean;
        float rs = rsqrtf(var + BN_EPS);
        float sc = g_[c] * rs, sh = b_[c] - mean * sc;
        for (int r = 0; r < NG; r++) {
            float v = h[(seg * NG + r) * DD + c];
            h[(seg * NG + r) * DD + c] = fmaxf(v * sc + sh, 0.f);
        }
    }
}

__global__ __launch_bounds__(128) void k_fc2(const float* __restrict__ h,
                                             const float* __restrict__ W,
                                             const float* __restrict__ bias,
                                             float* __restrict__ out) {
    __shared__ float row[DD];
    int g = blockIdx.x;
    int t = threadIdx.x;
    for (int i = t; i < DD; i += 128) row[i] = h[g * DD + i];
    __syncthreads();
    float acc = 0.f;
    for (int k = 0; k < DD; k++) acc += row[k] * W[k * NHID + t];
    out[g * NHID + t] = acc + bias[t];
}

// ------------------------------------------------------------------ regressor
__global__ __launch_bounds__(128) void k_reg(const float* __restrict__ gout,
                                             const float* __restrict__ W1,
                                             const float* __restrict__ b1,
                                             const float* __restrict__ W2,
                                             const float* __restrict__ b2,
                                             float* __restrict__ out) {
    __shared__ float x[256];
    __shared__ float red[128];
    int g = blockIdx.x;
    int t = threadIdx.x;
    x[t] = gout[g * NHID + t];
    x[t + 128] = gout[(NG + g) * NHID + t];
    __syncthreads();
    float acc = b1[t];
    for (int k = 0; k < 256; k++) acc += x[k] * W1[k * NHID + t];
    acc = fmaxf(acc, 0.f);
    red[t] = acc * W2[t];
    __syncthreads();
    for (int off = 64; off; off >>= 1) {
        if (t < off) red[t] += red[t + off];
        __syncthreads();
    }
    if (t == 0) out[g] = red[0] + b2[0];
}

// ==================================================================== launch
extern "C" void kernel_launch(void* const* d_in, const int* in_sizes, int n_in,
                              void* d_out, int out_size, void* d_ws, size_t ws_size,
                              hipStream_t stream) {
    const float* wl_x = (const float*)d_in[0];
    const float* mt_x = (const float*)d_in[1];
    const int* wl_ei = (const int*)d_in[2];
    const int* mt_ei = (const int*)d_in[3];
    const int* wl_batch = (const int*)d_in[4];
    const int* mt_batch = (const int*)d_in[5];
    const float* gin1_W1 = (const float*)d_in[6];
    const float* gin1_b1 = (const float*)d_in[7];
    const float* gin1_W2 = (const float*)d_in[8];
    const float* gin1_b2 = (const float*)d_in[9];
    const float* bn1_g = (const float*)d_in[10];
    const float* bn1_b = (const float*)d_in[11];
    const float* gin2_W1 = (const float*)d_in[12];
    const float* gin2_b1 = (const float*)d_in[13];
    const float* gin2_W2 = (const float*)d_in[14];
    const float* gin2_b2 = (const float*)d_in[15];
    const float* bn2_g = (const float*)d_in[16];
    const float* bn2_b = (const float*)d_in[17];
    const float* gat_W = (const float*)d_in[18];
    const float* gat_as = (const float*)d_in[19];
    const float* gat_ad = (const float*)d_in[20];
    const float* gat_bias = (const float*)d_in[21];
    const float* fc_W1 = (const float*)d_in[22];
    const float* fc_b1 = (const float*)d_in[23];
    const float* fc_bn_g = (const float*)d_in[24];
    const float* fc_bn_b = (const float*)d_in[25];
    const float* fc_W2 = (const float*)d_in[26];
    const float* fc_b2 = (const float*)d_in[27];
    const float* reg_W1 = (const float*)d_in[28];
    const float* reg_b1 = (const float*)d_in[29];
    const float* reg_W2 = (const float*)d_in[30];
    const float* reg_b2 = (const float*)d_in[31];
    float* out = (float*)d_out;

    char* ws = (char*)d_ws;
    size_t o = 0;
    auto alloc = [&](size_t bytes) {
        size_t r = o;
        o = (o + bytes + 255) & ~(size_t)255;
        return r;
    };
    unsigned short* hbA = (unsigned short*)(ws + alloc((size_t)NT * DD * 2)); // 61.4 MB
    unsigned short* hbB = (unsigned short*)(ws + alloc((size_t)NT * DD * 2)); // 61.4 MB
    float* xm = (float*)(ws + alloc((size_t)NT * DIN * 4));
    float* bufA = (float*)(ws + alloc((size_t)NT * DIN * 4));
    int* bm = (int*)(ws + alloc((size_t)NT * 4));
    int* cnt = (int*)(ws + alloc((size_t)NT * 4));
    int* rowptr = (int*)(ws + alloc((size_t)(NT + 1) * 4));
    int* cursor = (int*)(ws + alloc((size_t)NT * 4));
    int* colidx = (int*)(ws + alloc((size_t)2 * E1 * 4));
    float* a_s = (float*)(ws + alloc((size_t)NT * NH * 4));
    float* a_d = (float*)(ws + alloc((size_t)NT * NH * 4));
    float* bnsums = (float*)(ws + alloc(4 * DD * 4));
    float* bnsc = (float*)(ws + alloc(4 * DD * 4));
    float* partial = (float*)(ws + alloc((size_t)NGT * PSPLIT * DD * 4));
    float* pool = (float*)(ws + alloc((size_t)NGT * DD * 4));
    float* fch = (float*)(ws + alloc((size_t)NGT * DD * 4));
    float* gout = (float*)(ws + alloc((size_t)NGT * NHID * 4));
    unsigned short* Wt1 = (unsigned short*)(ws + alloc((size_t)DD * DD * 2));
    unsigned short* Wt2 = (unsigned short*)(ws + alloc((size_t)DD * DD * 2));
    unsigned short* Wt3 = (unsigned short*)(ws + alloc((size_t)DD * DD * 2));
    unsigned short* Wt4 = (unsigned short*)(ws + alloc((size_t)DD * DD * 2));
    (void)ws_size; (void)in_sizes; (void)n_in; (void)out_size;

    // one-time per launch: weights + merged inputs
    k_wconv<<<DD, 256, 0, stream>>>(gin1_W2, Wt1);
    k_wconv<<<DD, 256, 0, stream>>>(gin2_W1, Wt2);
    k_wconv<<<DD, 256, 0, stream>>>(gin2_W2, Wt3);
    k_wconv<<<DD, 256, 0, stream>>>(gat_W, Wt4);
    k_xmerge<<<(NT * DIN + 255) / 256, 256, 0, stream>>>(wl_x, mt_x, xm);
    k_bmerge<<<(NT + 255) / 256, 256, 0, stream>>>(wl_batch, mt_batch, bm);

    // merged CSR (mt node ids offset by N1)
    hipMemsetAsync(cnt, 0, (size_t)NT * 4, stream);
    k_hist2<<<512, 256, 0, stream>>>(wl_ei + E1, mt_ei + E1, cnt);
    k_scan2<<<1, 512, 0, stream>>>(cnt, rowptr, cursor, NT);
    k_scatter2<<<512, 256, 0, stream>>>(wl_ei, wl_ei + E1, mt_ei, mt_ei + E1,
                                        cursor, colidx);

    int gmm = ((NT + 255) / 256) * 4;   // 235 row blocks x 4 col tiles (adjacent)
    dim3 g20((NT + 63) / 64, 4);

    // GIN1
    k_gin1_agg<<<(NT + 3) / 4, 256, 0, stream>>>(xm, rowptr, colidx, bufA);
    k_gemm20<<<g20, 256, 0, stream>>>(bufA, gin1_W1, gin1_b1, hbA);
    k_gemm_mfma<0><<<gmm, 256, 0, stream>>>(hbA, Wt1, gin1_b2, hbB, nullptr,
                                            nullptr, nullptr, nullptr, NT);
    // bn1: stats + fin only; apply fused into aggregation
    hipMemsetAsync(bnsums, 0, 4 * DD * 4, stream);
    k_bn_stats2b<<<256, 256, 0, stream>>>(hbB, bnsums);
    k_bn_fin2<<<1, 512, 0, stream>>>(bnsums, bn1_g, bn1_b, bnsc);

    // GIN2 (agg applies bn1 scale/shift + relu on the fly)
    k_agg512f<<<(NT + 3) / 4, 256, 0, stream>>>(hbB, rowptr, colidx, bnsc, hbA);
    k_gemm_mfma<1><<<gmm, 256, 0, stream>>>(hbA, Wt2, gin2_b1, hbB, nullptr,
                                            nullptr, nullptr, nullptr, NT);
    k_gemm_mfma<0><<<gmm, 256, 0, stream>>>(hbB, Wt3, gin2_b2, hbA, nullptr,
                                            nullptr, nullptr, nullptr, NT);
    // bn2: stats + fin + in-place apply (GAT GEMM consumes applied values)
    hipMemsetAsync(bnsums, 0, 4 * DD * 4, stream);
    k_bn_stats2b<<<256, 256, 0, stream>>>(hbA, bnsums);
    k_bn_fin2<<<1, 512, 0, stream>>>(bnsums, bn2_g, bn2_b, bnsc);
    k_bn_apply_ip<<<2048, 256, 0, stream>>>(hbA, bnsc);

    // GAT (features bf16 -> hbB, logits a_s/a_d from fp32 accumulators)
    k_gemm_mfma<2><<<gmm, 256, 0, stream>>>(hbA, Wt4, nullptr, hbB, gat_as,
                                            gat_ad, a_s, a_d, NT);
    k_gat_gather<<<(NT + 3) / 4, 256, 0, stream>>>(hbB, a_s, a_d, rowptr, colidx,
                                                   hbA);
    k_pool1<<<dim3(NGT, PSPLIT), 256, 0, stream>>>(hbA, bm, partial);
    k_pool2<<<NGT, 512, 0, stream>>>(partial, bm, gat_bias, pool);

    // fc head (both branches at once)
    k_fc1<<<NGT, 256, 0, stream>>>(pool, fc_W1, fc_b1, fch);
    k_bn64_2<<<1, 512, 0, stream>>>(fch, fc_bn_g, fc_bn_b);
    k_fc2<<<NGT, 128, 0, stream>>>(fch, fc_W2, fc_b2, gout);

    k_reg<<<NG, 128, 0, stream>>>(gout, reg_W1, reg_b1, reg_W2, reg_b2, out);
}

// Round 15
// 1455.998 us; speedup vs baseline: 1.0096x; 1.0096x over previous
//
#include <hip/hip_runtime.h>
#include <hip/hip_bf16.h>
#include <math.h>

#define N1     30000          // nodes per branch
#define NT     60000          // merged nodes
#define E1     480000
#define NG     64             // graphs per branch
#define NGT    128            // merged graphs
#define DIN    20
#define DD     512
#define NH     4
#define CH     128
#define NHID   128
#define PSPLIT 8
#define BN_EPS 1e-5f

typedef __attribute__((ext_vector_type(8))) short bf16x8;
typedef __attribute__((ext_vector_type(4))) float f32x4;
typedef __attribute__((address_space(1))) const void cg_void;
typedef __attribute__((address_space(3))) void lds_void;

__device__ inline unsigned short f2b(float f) {
    __hip_bfloat16 h = __float2bfloat16(f);
    return *(unsigned short*)&h;
}
__device__ inline float b2f(unsigned short u) {
    return __uint_as_float(((unsigned)u) << 16);
}

// ------------------------------------------- merged input copy (x + batch ids)
__global__ __launch_bounds__(256) void k_merge(const float* __restrict__ xa,
                                               const float* __restrict__ xb,
                                               const int* __restrict__ ba,
                                               const int* __restrict__ bb,
                                               float* __restrict__ xm,
                                               int* __restrict__ bm) {
    int i = blockIdx.x * 256 + threadIdx.x;
    int tot = NT * DIN;
    if (i < tot) xm[i] = (i < N1 * DIN) ? xa[i] : xb[i - N1 * DIN];
    if (i < NT) bm[i] = (i < N1) ? ba[i] : bb[i - N1] + NG;
}

// ---------------------------------------------------------------- CSR build
__global__ __launch_bounds__(256) void k_hist2(const int* __restrict__ dwl,
                                               const int* __restrict__ dmt,
                                               int* __restrict__ cnt) {
    for (int e = blockIdx.x * blockDim.x + threadIdx.x; e < E1;
         e += gridDim.x * blockDim.x) {
        atomicAdd(&cnt[dwl[e]], 1);
        atomicAdd(&cnt[dmt[e] + N1], 1);
    }
}

__global__ __launch_bounds__(512) void k_scan2(const int* __restrict__ cnt,
                                               int* __restrict__ rowptr,
                                               int* __restrict__ cursor, int n) {
    __shared__ int sd[512];
    int t = threadIdx.x;
    int per = (n + 511) / 512;
    int lo = t * per, hi = lo + per;
    if (hi > n) hi = n;
    int s = 0;
    for (int i = lo; i < hi; ++i) s += cnt[i];
    sd[t] = s;
    __syncthreads();
    for (int off = 1; off < 512; off <<= 1) {
        int v = (t >= off) ? sd[t - off] : 0;
        __syncthreads();
        sd[t] += v;
        __syncthreads();
    }
    int run = sd[t] - s;
    for (int i = lo; i < hi; ++i) {
        rowptr[i] = run;
        cursor[i] = run;
        run += cnt[i];
    }
    if (t == 511) rowptr[n] = sd[511];
}

__global__ __launch_bounds__(256) void k_scatter2(const int* __restrict__ swl,
                                                  const int* __restrict__ dwl,
                                                  const int* __restrict__ smt,
                                                  const int* __restrict__ dmt,
                                                  int* __restrict__ cursor,
                                                  int* __restrict__ col) {
    for (int e = blockIdx.x * blockDim.x + threadIdx.x; e < E1;
         e += gridDim.x * blockDim.x) {
        int d0 = dwl[e];
        col[atomicAdd(&cursor[d0], 1)] = swl[e];
        int d1 = dmt[e] + N1;
        col[atomicAdd(&cursor[d1], 1)] = smt[e] + N1;
    }
}

// --------------------------- 4 weight conv+transpose fused into one dispatch
__global__ __launch_bounds__(256) void k_wconv4(const float* __restrict__ W0,
                                                const float* __restrict__ W1,
                                                const float* __restrict__ W2,
                                                const float* __restrict__ W3,
                                                unsigned short* __restrict__ T0,
                                                unsigned short* __restrict__ T1,
                                                unsigned short* __restrict__ T2,
                                                unsigned short* __restrict__ T3) {
    int wsel = blockIdx.x >> 9;
    int n = blockIdx.x & 511;
    const float* W = (wsel == 0) ? W0 : (wsel == 1) ? W1 : (wsel == 2) ? W2 : W3;
    unsigned short* T = (wsel == 0) ? T0 : (wsel == 1) ? T1 : (wsel == 2) ? T2 : T3;
    for (int k = threadIdx.x; k < DD; k += 256)
        T[n * DD + k] = f2b(W[k * DD + n]);
}

// ------------------------------------------------------------- GIN1 agg (20)
__global__ __launch_bounds__(256) void k_gin1_agg(const float* __restrict__ x,
                                                  const int* __restrict__ rowptr,
                                                  const int* __restrict__ col,
                                                  float* __restrict__ out) {
    int node = blockIdx.x * 4 + (threadIdx.x >> 6);
    int lane = threadIdx.x & 63;
    if (node >= NT) return;
    int p0 = rowptr[node], p1 = rowptr[node + 1];
    float acc = 0.f;
    if (lane < DIN) acc = x[(size_t)node * DIN + lane];
    for (int j = p0; j < p1; ++j) {
        int s = col[j];
        if (lane < DIN) acc += x[(size_t)s * DIN + lane];
    }
    if (lane < DIN) out[(size_t)node * DIN + lane] = acc;
}

// ------------------------------------- GEMM [NT,20]@[20,512]+relu -> bf16 out
__global__ __launch_bounds__(256) void k_gemm20(const float* __restrict__ A,
                                                const float* __restrict__ W,
                                                const float* __restrict__ bias,
                                                unsigned short* __restrict__ C) {
    __shared__ float Ws[DIN][128];
    __shared__ float As[64][DIN + 1];
    int t = threadIdx.x;
    int row0 = blockIdx.x * 64;
    int col0 = blockIdx.y * 128;
    for (int i = t; i < DIN * 128; i += 256) {
        int k = i >> 7, c = i & 127;
        Ws[k][c] = W[k * DD + col0 + c];
    }
    for (int i = t; i < 64 * DIN; i += 256) {
        int r = i / DIN, k = i % DIN;
        int rr = row0 + r;
        if (rr >= NT) rr = NT - 1;
        As[r][k] = A[(size_t)rr * DIN + k];
    }
    __syncthreads();
    int c4 = (t & 31) * 4;
    int r0 = (t >> 5) * 8;
    float acc[8][4];
#pragma unroll
    for (int i = 0; i < 8; i++)
#pragma unroll
        for (int j = 0; j < 4; j++) acc[i][j] = 0.f;
    for (int k = 0; k < DIN; k++) {
        float4 b = *(const float4*)&Ws[k][c4];
#pragma unroll
        for (int i = 0; i < 8; i++) {
            float a = As[r0 + i][k];
            acc[i][0] += a * b.x; acc[i][1] += a * b.y;
            acc[i][2] += a * b.z; acc[i][3] += a * b.w;
        }
    }
    float4 bb = *(const float4*)&bias[col0 + c4];
#pragma unroll
    for (int i = 0; i < 8; i++) {
        int r = row0 + r0 + i;
        if (r < NT) {
            short4 o;
            o.x = (short)f2b(fmaxf(acc[i][0] + bb.x, 0.f));
            o.y = (short)f2b(fmaxf(acc[i][1] + bb.y, 0.f));
            o.z = (short)f2b(fmaxf(acc[i][2] + bb.z, 0.f));
            o.w = (short)f2b(fmaxf(acc[i][3] + bb.w, 0.f));
            *(short4*)&C[(size_t)r * DD + col0 + c4] = o;
        }
    }
}

// ------------------------------- MFMA GEMM [M,512](bf16) @ Wt[512,512](bf16^T)
// 256x128 tile, BK=64, gload_lds staging, source-side XOR swizzle.
// 4 waves; wave w owns rows [w*64, w*64+64) x all 128 cols: acc[4][8].
// MODE: 0 = bf16 out + bias; 1 = + relu; 2 = no bias + a_s/a_d epilogue (GAT)
template <int MODE>
__global__ __launch_bounds__(256) void k_gemm_mfma(
    const unsigned short* __restrict__ A, const unsigned short* __restrict__ Wt,
    const float* __restrict__ bias, unsigned short* __restrict__ Cb,
    const float* __restrict__ att_s, const float* __restrict__ att_d,
    float* __restrict__ as_o, float* __restrict__ ad_o, int M) {
    __shared__ unsigned short AsU[256 * 64];   // 32 KB; reused as st[128][128]
    __shared__ unsigned short BsU[128 * 64];   // 16 KB
    __shared__ float s_att[2 * 256];           // MODE 2 only

    int t = threadIdx.x;
    int lane = t & 63;
    int w = t >> 6;
    int bid = blockIdx.x;
    int row0 = (bid >> 2) * 256;
    int ct = bid & 3;
    int col0 = ct * 128;

    int l8 = lane >> 3;                 // row within 8-row staging group
    int swz = (lane & 7) ^ l8;          // source k-slot permutation

    f32x4 acc[4][8];
#pragma unroll
    for (int i = 0; i < 4; i++)
#pragma unroll
        for (int j = 0; j < 8; j++) acc[i][j] = (f32x4){0.f, 0.f, 0.f, 0.f};

    int fr = lane & 15, fq = lane >> 4, f7 = lane & 7;

    for (int s = 0; s < 8; ++s) {
        int k0 = s * 64;
        __syncthreads();                 // prev-step fragment reads done
        // A: wave w stages rows [w*64, w*64+64): 8 gloads of 8 rows
#pragma unroll
        for (int q = 0; q < 8; q++) {
            int rowbase = w * 64 + q * 8;
            int gr = row0 + rowbase + l8;
            if (gr >= M) gr = M - 1;
            const unsigned short* srcA = A + (size_t)gr * DD + k0 + swz * 8;
            __builtin_amdgcn_global_load_lds((cg_void*)srcA,
                                             (lds_void*)(AsU + rowbase * 64),
                                             16, 0, 0);
        }
        // B: wave w stages rows [w*32, w*32+32): 4 gloads
#pragma unroll
        for (int q = 0; q < 4; q++) {
            int rowbase = w * 32 + q * 8;
            const unsigned short* srcB = Wt +
                (size_t)(col0 + rowbase + l8) * DD + k0 + swz * 8;
            __builtin_amdgcn_global_load_lds((cg_void*)srcB,
                                             (lds_void*)(BsU + rowbase * 64),
                                             16, 0, 0);
        }
        __syncthreads();                 // vmcnt(0) drained by compiler
#pragma unroll
        for (int kk = 0; kk < 2; kk++) {
            bf16x8 am[4], bn[8];
#pragma unroll
            for (int i = 0; i < 4; i++) {
                int row = w * 64 + i * 16 + fr;       // row&7 == lane&7
                int ks = (kk * 4 + fq) ^ f7;
                am[i] = *(const bf16x8*)&AsU[row * 64 + ks * 8];
            }
#pragma unroll
            for (int j = 0; j < 8; j++) {
                int row = j * 16 + fr;
                int ks = (kk * 4 + fq) ^ f7;
                bn[j] = *(const bf16x8*)&BsU[row * 64 + ks * 8];
            }
#pragma unroll
            for (int i = 0; i < 4; i++)
#pragma unroll
                for (int j = 0; j < 8; j++)
                    acc[i][j] = __builtin_amdgcn_mfma_f32_16x16x32_bf16(
                        am[i], bn[j], acc[i][j], 0, 0, 0);
        }
    }

    // ---------------- epilogue: 2-half LDS-staged coalesced store ----------
    __syncthreads();                     // all fragment reads done; reuse AsU
    unsigned short* st = AsU;            // [128][128] ushort = 32KB
    float bv[8], fa[8], fd[8];
#pragma unroll
    for (int j = 0; j < 8; j++) {
        int c = j * 16 + fr;
        if (MODE == 2) {
            fa[j] = att_s[ct * CH + c];
            fd[j] = att_d[ct * CH + c];
        } else {
            bv[j] = bias[col0 + c];
        }
    }
    if (MODE == 2) { s_att[t] = 0.f; s_att[256 + t] = 0.f; }
    __syncthreads();
    if (MODE == 2) {
#pragma unroll
        for (int i = 0; i < 4; i++) {
#pragma unroll
            for (int r = 0; r < 4; r++) {
                int lrow = w * 64 + i * 16 + fq * 4 + r;
                float ss = 0.f, sd = 0.f;
#pragma unroll
                for (int j = 0; j < 8; j++) {
                    ss += acc[i][j][r] * fa[j];
                    sd += acc[i][j][r] * fd[j];
                }
                atomicAdd(&s_att[lrow], ss);
                atomicAdd(&s_att[256 + lrow], sd);
            }
        }
    }
#pragma unroll
    for (int h = 0; h < 2; h++) {
        if ((w >> 1) == h) {             // waves 2h,2h+1 own this 128-row half
            int lr0 = (w & 1) * 64;
#pragma unroll
            for (int i = 0; i < 4; i++) {
#pragma unroll
                for (int r = 0; r < 4; r++) {
                    int lrow = lr0 + i * 16 + fq * 4 + r;
#pragma unroll
                    for (int j = 0; j < 8; j++) {
                        float v = acc[i][j][r];
                        if (MODE != 2) {
                            v += bv[j];
                            if (MODE == 1) v = fmaxf(v, 0.f);
                        }
                        st[lrow * 128 + j * 16 + fr] = f2b(v);
                    }
                }
            }
        }
        __syncthreads();                 // st writes (+ h=0: s_att atomics) done
        // coalesced readout: each 16-lane group covers one full 256B row
#pragma unroll
        for (int i = 0; i < 8; i++) {
            int idx = i * 256 + t;
            int row = idx >> 4, seg = idx & 15;
            int grow = row0 + h * 128 + row;
            if (grow < M) {
                int4 v = *(const int4*)&st[row * 128 + seg * 8];
                *(int4*)&Cb[(size_t)grow * DD + col0 + seg * 8] = v;
            }
        }
        __syncthreads();                 // readout done before st reuse
    }
    if (MODE == 2) {
        // t in 0..255 covers all 256 tile rows exactly once
        int grow = row0 + t;
        if (grow < M) {
            as_o[grow * NH + ct] = s_att[t];
            ad_o[grow * NH + ct] = s_att[256 + t];
        }
    }
}

// --------------------------- BatchNorm over bf16, two branch segments
__global__ __launch_bounds__(256) void k_bn_stats2b(const unsigned short* __restrict__ h,
                                                    float* __restrict__ sums) {
    int t = threadIdx.x;                 // channels 2t, 2t+1
    float sa[2] = {0.f, 0.f}, qa[2] = {0.f, 0.f};
    float sb[2] = {0.f, 0.f}, qb[2] = {0.f, 0.f};
    for (int r = blockIdx.x; r < NT; r += gridDim.x) {
        unsigned u = ((const unsigned*)(h + (size_t)r * DD))[t];
        float va = b2f((unsigned short)(u & 0xffff));
        float vb = b2f((unsigned short)(u >> 16));
        int seg = (r >= N1);
        sa[seg] += va; qa[seg] += va * va;
        sb[seg] += vb; qb[seg] += vb * vb;
    }
    int c = 2 * t;
#pragma unroll
    for (int seg = 0; seg < 2; ++seg) {
        atomicAdd(&sums[seg * DD + c], sa[seg]);
        atomicAdd(&sums[seg * DD + c + 1], sb[seg]);
        atomicAdd(&sums[2 * DD + seg * DD + c], qa[seg]);
        atomicAdd(&sums[2 * DD + seg * DD + c + 1], qb[seg]);
    }
}

__global__ __launch_bounds__(512) void k_bn_fin2(const float* __restrict__ sums,
                                                 const float* __restrict__ g,
                                                 const float* __restrict__ b,
                                                 float* __restrict__ sc) {
    int c = threadIdx.x;
#pragma unroll
    for (int seg = 0; seg < 2; ++seg) {
        float mean = sums[seg * DD + c] / (float)N1;
        float var = sums[2 * DD + seg * DD + c] / (float)N1 - mean * mean;
        float rs = rsqrtf(var + BN_EPS);
        float s = g[c] * rs;
        sc[seg * DD + c] = s;
        sc[2 * DD + seg * DD + c] = b[c] - mean * s;
    }
}

// BN apply + relu, in-place on bf16 buffer
__global__ __launch_bounds__(256) void k_bn_apply_ip(unsigned short* __restrict__ h,
                                                     const float* __restrict__ sc) {
    int total = NT * (DD / 8);
    for (int i = blockIdx.x * blockDim.x + threadIdx.x; i < total;
         i += gridDim.x * blockDim.x) {
        int4 v = ((int4*)h)[i];
        unsigned short* u = (unsigned short*)&v;
        int row = i >> 6;
        int seg = (row >= N1);
        int c = (i & 63) * 8;
        const float* scale = sc + seg * DD;
        const float* shift = sc + 2 * DD + seg * DD;
#pragma unroll
        for (int k = 0; k < 8; k++) {
            float f = b2f(u[k]) * scale[c + k] + shift[c + k];
            u[k] = f2b(fmaxf(f, 0.f));
        }
        ((int4*)h)[i] = v;
    }
}

// ---- D=512 neighborhood sum fused with BN apply+relu, 4-edge unrolled ----
__global__ __launch_bounds__(256) void k_agg512f(const unsigned short* __restrict__ h,
                                                 const int* __restrict__ rowptr,
                                                 const int* __restrict__ col,
                                                 const float* __restrict__ sc,
                                                 unsigned short* __restrict__ out) {
    int node = blockIdx.x * 4 + (threadIdx.x >> 6);
    int lane = threadIdx.x & 63;
    if (node >= NT) return;
    int seg = (node >= N1);          // neighbors share the node's branch segment
    int cb = lane * 8;
    float scl[8], shf[8];
    *(float4*)&scl[0] = *(const float4*)&sc[seg * DD + cb];
    *(float4*)&scl[4] = *(const float4*)&sc[seg * DD + cb + 4];
    *(float4*)&shf[0] = *(const float4*)&sc[2 * DD + seg * DD + cb];
    *(float4*)&shf[4] = *(const float4*)&sc[2 * DD + seg * DD + cb + 4];

    size_t base = (size_t)node * DD + cb;
    float acc[8];
    {
        int4 v = *(const int4*)&h[base];
        const unsigned short* u = (const unsigned short*)&v;
#pragma unroll
        for (int i = 0; i < 8; i++)
            acc[i] = fmaxf(b2f(u[i]) * scl[i] + shf[i], 0.f);
    }
    int p0 = rowptr[node], p1 = rowptr[node + 1];
    int j = p0;
    for (; j + 3 < p1; j += 4) {
        int s0 = col[j], s1 = col[j + 1], s2 = col[j + 2], s3 = col[j + 3];
        int4 v0 = *(const int4*)&h[(size_t)s0 * DD + cb];
        int4 v1 = *(const int4*)&h[(size_t)s1 * DD + cb];
        int4 v2 = *(const int4*)&h[(size_t)s2 * DD + cb];
        int4 v3 = *(const int4*)&h[(size_t)s3 * DD + cb];
        const unsigned short* u0 = (const unsigned short*)&v0;
        const unsigned short* u1 = (const unsigned short*)&v1;
        const unsigned short* u2 = (const unsigned short*)&v2;
        const unsigned short* u3 = (const unsigned short*)&v3;
#pragma unroll
        for (int i = 0; i < 8; i++)
            acc[i] += fmaxf(b2f(u0[i]) * scl[i] + shf[i], 0.f) +
                      fmaxf(b2f(u1[i]) * scl[i] + shf[i], 0.f) +
                      fmaxf(b2f(u2[i]) * scl[i] + shf[i], 0.f) +
                      fmaxf(b2f(u3[i]) * scl[i] + shf[i], 0.f);
    }
    for (; j < p1; ++j) {
        int4 v0 = *(const int4*)&h[(size_t)col[j] * DD + cb];
        const unsigned short* u0 = (const unsigned short*)&v0;
#pragma unroll
        for (int i = 0; i < 8; i++)
            acc[i] += fmaxf(b2f(u0[i]) * scl[i] + shf[i], 0.f);
    }
    int4 o;
    unsigned short* uo = (unsigned short*)&o;
#pragma unroll
    for (int i = 0; i < 8; i++) uo[i] = f2b(acc[i]);
    *(int4*)&out[base] = o;
}

// ------- GAT gather: inline softmax weights, 4-edge unrolled, bf16 output
__global__ __launch_bounds__(256) void k_gat_gather(
    const unsigned short* __restrict__ hh, const float* __restrict__ a_s,
    const float* __restrict__ a_d, const int* __restrict__ rowptr,
    const int* __restrict__ col, unsigned short* __restrict__ outB) {
    int node = blockIdx.x * 4 + (threadIdx.x >> 6);
    int lane = threadIdx.x & 63;
    if (node >= NT) return;
    int h = lane >> 4;
    int idx4 = node * NH + h;
    float adi = a_d[idx4];
    float e = a_s[idx4] + adi;
    e = (e > 0.f) ? e : 0.2f * e;
    float ws = __expf(e);
    float den = ws;
    float acc[8];
    {
        int4 v = *(const int4*)&hh[(size_t)node * DD + lane * 8];
        const unsigned short* u = (const unsigned short*)&v;
#pragma unroll
        for (int i = 0; i < 8; i++) acc[i] = ws * b2f(u[i]);
    }
    int p0 = rowptr[node], p1 = rowptr[node + 1];
    int j = p0;
    for (; j + 3 < p1; j += 4) {
        int s0 = col[j], s1 = col[j + 1], s2 = col[j + 2], s3 = col[j + 3];
        float e0 = a_s[s0 * NH + h] + adi;
        float e1 = a_s[s1 * NH + h] + adi;
        float e2 = a_s[s2 * NH + h] + adi;
        float e3 = a_s[s3 * NH + h] + adi;
        e0 = (e0 > 0.f) ? e0 : 0.2f * e0;
        e1 = (e1 > 0.f) ? e1 : 0.2f * e1;
        e2 = (e2 > 0.f) ? e2 : 0.2f * e2;
        e3 = (e3 > 0.f) ? e3 : 0.2f * e3;
        float w0 = __expf(e0), w1 = __expf(e1);
        float w2 = __expf(e2), w3 = __expf(e3);
        int4 v0 = *(const int4*)&hh[(size_t)s0 * DD + lane * 8];
        int4 v1 = *(const int4*)&hh[(size_t)s1 * DD + lane * 8];
        int4 v2 = *(const int4*)&hh[(size_t)s2 * DD + lane * 8];
        int4 v3 = *(const int4*)&hh[(size_t)s3 * DD + lane * 8];
        const unsigned short* u0 = (const unsigned short*)&v0;
        const unsigned short* u1 = (const unsigned short*)&v1;
        const unsigned short* u2 = (const unsigned short*)&v2;
        const unsigned short* u3 = (const unsigned short*)&v3;
#pragma unroll
        for (int i = 0; i < 8; i++)
            acc[i] += w0 * b2f(u0[i]) + w1 * b2f(u1[i]) +
                      w2 * b2f(u2[i]) + w3 * b2f(u3[i]);
        den += w0 + w1 + w2 + w3;
    }
    for (; j < p1; ++j) {
        int s0 = col[j];
        float e0 = a_s[s0 * NH + h] + adi;
        e0 = (e0 > 0.f) ? e0 : 0.2f * e0;
        float w0 = __expf(e0);
        int4 v0 = *(const int4*)&hh[(size_t)s0 * DD + lane * 8];
        const unsigned short* u0 = (const unsigned short*)&v0;
#pragma unroll
        for (int i = 0; i < 8; i++) acc[i] += w0 * b2f(u0[i]);
        den += w0;
    }
    float inv = 1.f / den;
    int4 o;
    unsigned short* uo = (unsigned short*)&o;
#pragma unroll
    for (int i = 0; i < 8; i++) uo[i] = f2b(acc[i] * inv);
    *(int4*)&outB[(size_t)node * DD + lane * 8] = o;
}

// ------------------------- two-stage segmented add-pool (sorted merged batch)
__device__ inline void graph_range(const int* __restrict__ bm, int g,
                                   int& start, int& end) {
    int lo = 0, hi = NT;
    while (lo < hi) { int m = (lo + hi) >> 1; if (bm[m] < g) lo = m + 1; else hi = m; }
    start = lo;
    hi = NT;
    while (lo < hi) { int m = (lo + hi) >> 1; if (bm[m] < g + 1) lo = m + 1; else hi = m; }
    end = lo;
}

__global__ __launch_bounds__(256) void k_pool1(const unsigned short* __restrict__ gatout,
                                               const int* __restrict__ bm,
                                               float* __restrict__ partial) {
    int g = blockIdx.x;
    int s = blockIdx.y;
    int t = threadIdx.x;                 // channels 2t, 2t+1
    int start, end;
    graph_range(bm, g, start, end);
    float a0 = 0.f, a1 = 0.f;
    for (int n = start + s; n < end; n += PSPLIT) {
        unsigned u = ((const unsigned*)(gatout + (size_t)n * DD))[t];
        a0 += b2f((unsigned short)(u & 0xffff));
        a1 += b2f((unsigned short)(u >> 16));
    }
    float* p = partial + ((size_t)g * PSPLIT + s) * DD;
    p[2 * t] = a0;
    p[2 * t + 1] = a1;
}

__global__ __launch_bounds__(512) void k_pool2(const float* __restrict__ partial,
                                               const int* __restrict__ bm,
                                               const float* __restrict__ bias,
                                               float* __restrict__ pool) {
    int g = blockIdx.x;
    int c = threadIdx.x;
    int start, end;
    graph_range(bm, g, start, end);
    float acc = 0.f;
#pragma unroll
    for (int s = 0; s < PSPLIT; ++s)
        acc += partial[((size_t)g * PSPLIT + s) * DD + c];
    pool[g * DD + c] = acc + (float)(end - start) * bias[c];
}

// ------------------------------------------------------------------- fc head
__global__ __launch_bounds__(256) void k_fc1(const float* __restrict__ gin,
                                             const float* __restrict__ W,
                                             const float* __restrict__ bias,
                                             float* __restrict__ out) {
    __shared__ float row[DD];
    int g = blockIdx.x;
    int t = threadIdx.x;
    row[t] = gin[g * DD + t];
    row[t + 256] = gin[g * DD + t + 256];
    __syncthreads();
    for (int cc = 0; cc < 2; ++cc) {
        int c = t + cc * 256;
        float acc = 0.f;
        for (int k = 0; k < DD; k++) acc += row[k] * W[k * DD + c];
        out[g * DD + c] = acc + bias[c];
    }
}

__global__ __launch_bounds__(512) void k_bn64_2(float* __restrict__ h,
                                                const float* __restrict__ g_,
                                                const float* __restrict__ b_) {
    int c = threadIdx.x;
#pragma unroll
    for (int seg = 0; seg < 2; ++seg) {
        float s = 0.f, q = 0.f;
        for (int r = 0; r < NG; r++) {
            float v = h[(seg * NG + r) * DD + c];
            s += v; q += v * v;
        }
        float mean = s / (float)NG;
        float var = q / (float)NG - mean * mean;
        float rs = rsqrtf(var + BN_EPS);
        float sc = g_[c] * rs, sh = b_[c] - mean * sc;
        for (int r = 0; r < NG; r++) {
            float v = h[(seg * NG + r) * DD + c];
            h[(seg * NG + r) * DD + c] = fmaxf(v * sc + sh, 0.f);
        }
    }
}

__global__ __launch_bounds__(128) void k_fc2(const float* __restrict__ h,
                                             const float* __restrict__ W,
                                             const float* __restrict__ bias,
                                             float* __restrict__ out) {
    __shared__ float row[DD];
    int g = blockIdx.x;
    int t = threadIdx.x;
    for (int i = t; i < DD; i += 128) row[i] = h[g * DD + i];
    __syncthreads();
    float acc = 0.f;
    for (int k = 0; k < DD; k++) acc += row[k] * W[k * NHID + t];
    out[g * NHID + t] = acc + bias[t];
}

// ------------------------------------------------------------------ regressor
__global__ __launch_bounds__(128) void k_reg(const float* __restrict__ gout,
                                             const float* __restrict__ W1,
                                             const float* __restrict__ b1,
                                             const float* __restrict__ W2,
                                             const float* __restrict__ b2,
                                             float* __restrict__ out) {
    __shared__ float x[256];
    __shared__ float red[128];
    int g = blockIdx.x;
    int t = threadIdx.x;
    x[t] = gout[g * NHID + t];
    x[t + 128] = gout[(NG + g) * NHID + t];
    __syncthreads();
    float acc = b1[t];
    for (int k = 0; k < 256; k++) acc += x[k] * W1[k * NHID + t];
    acc = fmaxf(acc, 0.f);
    red[t] = acc * W2[t];
    __syncthreads();
    for (int off = 64; off; off >>= 1) {
        if (t < off) red[t] += red[t + off];
        __syncthreads();
    }
    if (t == 0) out[g] = red[0] + b2[0];
}

// ==================================================================== launch
extern "C" void kernel_launch(void* const* d_in, const int* in_sizes, int n_in,
                              void* d_out, int out_size, void* d_ws, size_t ws_size,
                              hipStream_t stream) {
    const float* wl_x = (const float*)d_in[0];
    const float* mt_x = (const float*)d_in[1];
    const int* wl_ei = (const int*)d_in[2];
    const int* mt_ei = (const int*)d_in[3];
    const int* wl_batch = (const int*)d_in[4];
    const int* mt_batch = (const int*)d_in[5];
    const float* gin1_W1 = (const float*)d_in[6];
    const float* gin1_b1 = (const float*)d_in[7];
    const float* gin1_W2 = (const float*)d_in[8];
    const float* gin1_b2 = (const float*)d_in[9];
    const float* bn1_g = (const float*)d_in[10];
    const float* bn1_b = (const float*)d_in[11];
    const float* gin2_W1 = (const float*)d_in[12];
    const float* gin2_b1 = (const float*)d_in[13];
    const float* gin2_W2 = (const float*)d_in[14];
    const float* gin2_b2 = (const float*)d_in[15];
    const float* bn2_g = (const float*)d_in[16];
    const float* bn2_b = (const float*)d_in[17];
    const float* gat_W = (const float*)d_in[18];
    const float* gat_as = (const float*)d_in[19];
    const float* gat_ad = (const float*)d_in[20];
    const float* gat_bias = (const float*)d_in[21];
    const float* fc_W1 = (const float*)d_in[22];
    const float* fc_b1 = (const float*)d_in[23];
    const float* fc_bn_g = (const float*)d_in[24];
    const float* fc_bn_b = (const float*)d_in[25];
    const float* fc_W2 = (const float*)d_in[26];
    const float* fc_b2 = (const float*)d_in[27];
    const float* reg_W1 = (const float*)d_in[28];
    const float* reg_b1 = (const float*)d_in[29];
    const float* reg_W2 = (const float*)d_in[30];
    const float* reg_b2 = (const float*)d_in[31];
    float* out = (float*)d_out;

    char* ws = (char*)d_ws;
    size_t o = 0;
    auto alloc = [&](size_t bytes) {
        size_t r = o;
        o = (o + bytes + 255) & ~(size_t)255;
        return r;
    };
    unsigned short* hbA = (unsigned short*)(ws + alloc((size_t)NT * DD * 2)); // 61.4 MB
    unsigned short* hbB = (unsigned short*)(ws + alloc((size_t)NT * DD * 2)); // 61.4 MB
    float* xm = (float*)(ws + alloc((size_t)NT * DIN * 4));
    float* bufA = (float*)(ws + alloc((size_t)NT * DIN * 4));
    int* bm = (int*)(ws + alloc((size_t)NT * 4));
    int* cnt = (int*)(ws + alloc((size_t)NT * 4));
    int* rowptr = (int*)(ws + alloc((size_t)(NT + 1) * 4));
    int* cursor = (int*)(ws + alloc((size_t)NT * 4));
    int* colidx = (int*)(ws + alloc((size_t)2 * E1 * 4));
    float* a_s = (float*)(ws + alloc((size_t)NT * NH * 4));
    float* a_d = (float*)(ws + alloc((size_t)NT * NH * 4));
    float* bnsums = (float*)(ws + alloc(4 * DD * 4));
    float* bnsc = (float*)(ws + alloc(4 * DD * 4));
    float* partial = (float*)(ws + alloc((size_t)NGT * PSPLIT * DD * 4));
    float* pool = (float*)(ws + alloc((size_t)NGT * DD * 4));
    float* fch = (float*)(ws + alloc((size_t)NGT * DD * 4));
    float* gout = (float*)(ws + alloc((size_t)NGT * NHID * 4));
    unsigned short* Wt1 = (unsigned short*)(ws + alloc((size_t)DD * DD * 2));
    unsigned short* Wt2 = (unsigned short*)(ws + alloc((size_t)DD * DD * 2));
    unsigned short* Wt3 = (unsigned short*)(ws + alloc((size_t)DD * DD * 2));
    unsigned short* Wt4 = (unsigned short*)(ws + alloc((size_t)DD * DD * 2));
    (void)ws_size; (void)in_sizes; (void)n_in; (void)out_size;

    // one-time per launch: weights + merged inputs (fused dispatches)
    k_wconv4<<<4 * DD, 256, 0, stream>>>(gin1_W2, gin2_W1, gin2_W2, gat_W,
                                         Wt1, Wt2, Wt3, Wt4);
    k_merge<<<(NT * DIN + 255) / 256, 256, 0, stream>>>(wl_x, mt_x, wl_batch,
                                                        mt_batch, xm, bm);

    // merged CSR (mt node ids offset by N1)
    hipMemsetAsync(cnt, 0, (size_t)NT * 4, stream);
    k_hist2<<<512, 256, 0, stream>>>(wl_ei + E1, mt_ei + E1, cnt);
    k_scan2<<<1, 512, 0, stream>>>(cnt, rowptr, cursor, NT);
    k_scatter2<<<512, 256, 0, stream>>>(wl_ei, wl_ei + E1, mt_ei, mt_ei + E1,
                                        cursor, colidx);

    int gmm = ((NT + 255) / 256) * 4;   // 235 row blocks x 4 col tiles (adjacent)
    dim3 g20((NT + 63) / 64, 4);

    // GIN1
    k_gin1_agg<<<(NT + 3) / 4, 256, 0, stream>>>(xm, rowptr, colidx, bufA);
    k_gemm20<<<g20, 256, 0, stream>>>(bufA, gin1_W1, gin1_b1, hbA);
    k_gemm_mfma<0><<<gmm, 256, 0, stream>>>(hbA, Wt1, gin1_b2, hbB, nullptr,
                                            nullptr, nullptr, nullptr, NT);
    // bn1: stats + fin only; apply fused into aggregation
    hipMemsetAsync(bnsums, 0, 4 * DD * 4, stream);
    k_bn_stats2b<<<256, 256, 0, stream>>>(hbB, bnsums);
    k_bn_fin2<<<1, 512, 0, stream>>>(bnsums, bn1_g, bn1_b, bnsc);

    // GIN2 (agg applies bn1 scale/shift + relu on the fly)
    k_agg512f<<<(NT + 3) / 4, 256, 0, stream>>>(hbB, rowptr, colidx, bnsc, hbA);
    k_gemm_mfma<1><<<gmm, 256, 0, stream>>>(hbA, Wt2, gin2_b1, hbB, nullptr,
                                            nullptr, nullptr, nullptr, NT);
    k_gemm_mfma<0><<<gmm, 256, 0, stream>>>(hbB, Wt3, gin2_b2, hbA, nullptr,
                                            nullptr, nullptr, nullptr, NT);
    // bn2: stats + fin + in-place apply (GAT GEMM consumes applied values)
    hipMemsetAsync(bnsums, 0, 4 * DD * 4, stream);
    k_bn_stats2b<<<256, 256, 0, stream>>>(hbA, bnsums);
    k_bn_fin2<<<1, 512, 0, stream>>>(bnsums, bn2_g, bn2_b, bnsc);
    k_bn_apply_ip<<<2048, 256, 0, stream>>>(hbA, bnsc);

    // GAT (features bf16 -> hbB, logits a_s/a_d from fp32 accumulators)
    k_gemm_mfma<2><<<gmm, 256, 0, stream>>>(hbA, Wt4, nullptr, hbB, gat_as,
                                            gat_ad, a_s, a_d, NT);
    k_gat_gather<<<(NT + 3) / 4, 256, 0, stream>>>(hbB, a_s, a_d, rowptr, colidx,
                                                   hbA);
    k_pool1<<<dim3(NGT, PSPLIT), 256, 0, stream>>>(hbA, bm, partial);
    k_pool2<<<NGT, 512, 0, stream>>>(partial, bm, gat_bias, pool);

    // fc head (both branches at once)
    k_fc1<<<NGT, 256, 0, stream>>>(pool, fc_W1, fc_b1, fch);
    k_bn64_2<<<1, 512, 0, stream>>>(fch, fc_bn_g, fc_bn_b);
    k_fc2<<<NGT, 128, 0, stream>>>(fch, fc_W2, fc_b2, gout);

    k_reg<<<NG, 128, 0, stream>>>(gout, reg_W1, reg_b1, reg_W2, reg_b2, out);
}